// Round 10
// baseline (258.288 us; speedup 1.0000x reference)
//
#include <hip/hip_runtime.h>
#include <hip/hip_bf16.h>
#include <math.h>

#define N_SEQ 4096
#define D_MODEL 1024

typedef __attribute__((ext_vector_type(8))) short short8;
typedef __attribute__((ext_vector_type(4))) float f32x4;

__device__ __forceinline__ short f2bf(float f) {
  __hip_bfloat16 h = __float2bfloat16(f);
  return *reinterpret_cast<short*>(&h);
}
__device__ __forceinline__ float bf2f(short h) {
  return __uint_as_float(((unsigned)(unsigned short)h) << 16);
}

// async global->LDS, 16B per lane. LDS dest must be wave-uniform base + lane*16.
__device__ __forceinline__ void gload16(const short* g, short* l) {
  __builtin_amdgcn_global_load_lds(
      (const __attribute__((address_space(1))) void*)g,
      (__attribute__((address_space(3))) void*)l, 16, 0, 0);
}

// ---------------------------------------------------------------------------
// XOR-swizzled staging (256 thr): tile ROWS x 64 shorts. Slot s (16B):
// r = s>>3, c8 = (s&7)^(r&7) -> fragment ds_read_b128 hits all 32 banks
// (2-way, free — verified R4: conflicts 6.5e6 -> 0). HL: row = [hi 32 | lo 32].
// ---------------------------------------------------------------------------
template <int ROWS, bool HL>
__device__ __forceinline__ void stage_sw(const short* __restrict__ hi,
                                         const short* __restrict__ lo, int ld,
                                         int r0, int k0, short* dst, int tid) {
#pragma unroll
  for (int i = 0; i < ROWS * 8 / 256; ++i) {
    const int s = i * 256 + tid;
    const int r = s >> 3;
    const int c8 = (s & 7) ^ (r & 7);
    const short* src;
    int col;
    if (HL) {
      src = (c8 < 4) ? hi : lo;
      col = (c8 & 3) * 8;
    } else {
      src = hi;
      col = c8 * 8;
    }
    gload16(&src[(size_t)(r0 + r) * ld + k0 + col], &dst[s * 8]);
  }
}

// HL inner step (KSTEP=32): MI x NIv wave tile, 3-product split-bf16.
// reads/MFMA = 2(MI+NIv)/(3*MI*NIv): MI4/NI4 -> 0.33 (MFMA-bound).
template <int MI, int NIv>
__device__ __forceinline__ void hl_step(const short* sA, const short* sB,
                                        int wm, int wn, int quad, int l15,
                                        f32x4 acc[MI][NIv]) {
  short8 a[MI], am[MI], b[NIv], bm[NIv];
#pragma unroll
  for (int mi = 0; mi < MI; ++mi) {
    const int rr = wm + mi * 16 + l15;
    a[mi] = *(const short8*)&sA[rr * 64 + ((quad ^ (rr & 7)) << 3)];
    am[mi] = *(const short8*)&sA[rr * 64 + (((quad + 4) ^ (rr & 7)) << 3)];
  }
#pragma unroll
  for (int ni = 0; ni < NIv; ++ni) {
    const int rr = wn + ni * 16 + l15;
    b[ni] = *(const short8*)&sB[rr * 64 + ((quad ^ (rr & 7)) << 3)];
    bm[ni] = *(const short8*)&sB[rr * 64 + (((quad + 4) ^ (rr & 7)) << 3)];
  }
#pragma unroll
  for (int mi = 0; mi < MI; ++mi)
#pragma unroll
    for (int ni = 0; ni < NIv; ++ni) {
      acc[mi][ni] = __builtin_amdgcn_mfma_f32_16x16x32_bf16(a[mi], b[ni],
                                                            acc[mi][ni], 0, 0, 0);
      acc[mi][ni] = __builtin_amdgcn_mfma_f32_16x16x32_bf16(a[mi], bm[ni],
                                                            acc[mi][ni], 0, 0, 0);
      acc[mi][ni] = __builtin_amdgcn_mfma_f32_16x16x32_bf16(am[mi], b[ni],
                                                            acc[mi][ni], 0, 0, 0);
    }
}

// non-HL inner step (KSTEP=64): two k=32 slices. reads/MFMA = (MI+NIv)/(MI*NIv).
template <int MI, int NIv>
__device__ __forceinline__ void bf_step(const short* sA, const short* sB,
                                        int wm, int wn, int quad, int l15,
                                        f32x4 acc[MI][NIv]) {
#pragma unroll
  for (int s = 0; s < 2; ++s) {
    short8 a[MI], b[NIv];
#pragma unroll
    for (int mi = 0; mi < MI; ++mi) {
      const int rr = wm + mi * 16 + l15;
      a[mi] = *(const short8*)&sA[rr * 64 + (((s * 4 + quad) ^ (rr & 7)) << 3)];
    }
#pragma unroll
    for (int ni = 0; ni < NIv; ++ni) {
      const int rr = wn + ni * 16 + l15;
      b[ni] = *(const short8*)&sB[rr * 64 + (((s * 4 + quad) ^ (rr & 7)) << 3)];
    }
#pragma unroll
    for (int mi = 0; mi < MI; ++mi)
#pragma unroll
      for (int ni = 0; ni < NIv; ++ni)
        acc[mi][ni] = __builtin_amdgcn_mfma_f32_16x16x32_bf16(
            a[mi], b[ni], acc[mi][ni], 0, 0, 0);
  }
}

// ---------------------------------------------------------------------------
// Fused rect dispatch, 512 blocks x 256 thr, 128x128 tiles, MI4/NI4:
//  blocks [0,256):  q = x @ wqk (HL 3-product, out split qh/ql)
//  blocks [256,512): vT = (x @ wov)^T (bf16 out, ldc 4096)
// Independent GEMMs co-resident (2/CU) fill each other's barrier drains.
// ---------------------------------------------------------------------------
__global__ __launch_bounds__(256, 2)
void fused_rect(const short* __restrict__ xh, const short* __restrict__ xl,
                const short* __restrict__ wqkTh, const short* __restrict__ wqkTl,
                const short* __restrict__ wovT, short* __restrict__ qh,
                short* __restrict__ ql, short* __restrict__ vT) {
  __shared__ short sA[128 * 64];
  __shared__ short sB[128 * 64];
  const int tid = threadIdx.x;
  const int w = tid >> 6, lane = tid & 63;
  const int quad = lane >> 4, l15 = lane & 15;
  const int wm = (w >> 1) * 64, wn = (w & 1) * 64;

  f32x4 acc[4][4];
#pragma unroll
  for (int mi = 0; mi < 4; ++mi)
#pragma unroll
    for (int ni = 0; ni < 4; ++ni)
#pragma unroll
      for (int r = 0; r < 4; ++r) acc[mi][ni][r] = 0.f;

  if (blockIdx.x < 256) {
    // ---- qproj: 32x8 grid of 128x128 over 4096x1024 ----
    const int mt = blockIdx.x >> 3, nt = blockIdx.x & 7;
    const int m0 = mt * 128, n0 = nt * 128;
    for (int kt = 0; kt < 32; ++kt) {
      const int k0 = kt * 32;
      stage_sw<128, true>(xh, xl, 1024, m0, k0, sA, tid);
      stage_sw<128, true>(wqkTh, wqkTl, 1024, n0, k0, sB, tid);
      __syncthreads();
      hl_step<4, 4>(sA, sB, wm, wn, quad, l15, acc);
      __syncthreads();
    }
#pragma unroll
    for (int mi = 0; mi < 4; ++mi)
#pragma unroll
      for (int ni = 0; ni < 4; ++ni)
#pragma unroll
        for (int r = 0; r < 4; ++r) {
          const int row = m0 + wm + mi * 16 + quad * 4 + r;
          const int col = n0 + wn + ni * 16 + l15;
          const float v = acc[mi][ni][r];
          const short h = f2bf(v);
          qh[(size_t)row * 1024 + col] = h;
          ql[(size_t)row * 1024 + col] = f2bf(v - bf2f(h));
        }
  } else {
    // ---- vT = (x@wov)^T: C[m][n] = sum_d wovT[m][d] * xh[n][d]; 8x32 grid --
    const int f2 = blockIdx.x - 256;
    const int mt = f2 >> 5, nt = f2 & 31;
    const int m0 = mt * 128, n0 = nt * 128;
    for (int kt = 0; kt < 16; ++kt) {
      const int k0 = kt * 64;
      stage_sw<128, false>(wovT, nullptr, 1024, m0, k0, sA, tid);
      stage_sw<128, false>(xh, nullptr, 1024, n0, k0, sB, tid);
      __syncthreads();
      bf_step<4, 4>(sA, sB, wm, wn, quad, l15, acc);
      __syncthreads();
    }
#pragma unroll
    for (int mi = 0; mi < 4; ++mi)
#pragma unroll
      for (int ni = 0; ni < 4; ++ni)
#pragma unroll
        for (int r = 0; r < 4; ++r) {
          const int row = m0 + wm + mi * 16 + quad * 4 + r;
          const int col = n0 + wn + ni * 16 + l15;
          vT[(size_t)row * N_SEQ + col] = f2bf(acc[mi][ni][r]);
        }
  }
}

// ---------------------------------------------------------------------------
// QK causal, 528 blocks x 256 thr, 128x128 tiles, supertile-8 order,
// split-bf16 3-product, fp32 S out. (R8 config: 75.4 us, MfmaUtil 28.7.)
// ---------------------------------------------------------------------------
__global__ __launch_bounds__(256, 2)
void qk_causal(const short* __restrict__ qh, const short* __restrict__ ql,
               const short* __restrict__ xh, const short* __restrict__ xl,
               float* __restrict__ S) {
  __shared__ short sA[128 * 64];
  __shared__ short sB[128 * 64];
  const int tid = threadIdx.x;
  const int w = tid >> 6, lane = tid & 63;
  const int quad = lane >> 4, l15 = lane & 15;
  const int wm = (w >> 1) * 64, wn = (w & 1) * 64;

  // supertile-8 causal decode: super-rows R (mt in [8R,8R+8)), cum=32R^2+4R
  const int f = blockIdx.x;
  int R;
  if (f < 36) R = 0;
  else if (f < 136) R = 1;
  else if (f < 300) R = 2;
  else R = 3;
  const int rem = f - (32 * R * R + 4 * R);
  const int full = R << 6;
  int mt, nt;
  if (rem < full) {
    const int C = rem >> 6, ww = rem & 63;
    mt = 8 * R + (ww >> 3);
    nt = 8 * C + (ww & 7);
  } else {
    const int d = rem - full;
    int lm = 0;
    while ((lm + 1) * (lm + 2) / 2 <= d) ++lm;
    mt = 8 * R + lm;
    nt = 8 * R + d - lm * (lm + 1) / 2;
  }
  const int m0 = mt * 128, n0 = nt * 128;

  f32x4 acc[4][4];
#pragma unroll
  for (int mi = 0; mi < 4; ++mi)
#pragma unroll
    for (int ni = 0; ni < 4; ++ni)
#pragma unroll
      for (int r = 0; r < 4; ++r) acc[mi][ni][r] = 0.f;

  for (int kt = 0; kt < 32; ++kt) {
    const int k0 = kt * 32;
    stage_sw<128, true>(qh, ql, 1024, m0, k0, sA, tid);
    stage_sw<128, true>(xh, xl, 1024, n0, k0, sB, tid);
    __syncthreads();
    hl_step<4, 4>(sA, sB, wm, wn, quad, l15, acc);
    __syncthreads();
  }
#pragma unroll
  for (int mi = 0; mi < 4; ++mi)
#pragma unroll
    for (int ni = 0; ni < 4; ++ni)
#pragma unroll
      for (int r = 0; r < 4; ++r) {
        const int row = m0 + wm + mi * 16 + quad * 4 + r;
        const int col = n0 + wn + ni * 16 + l15;
        S[(size_t)row * N_SEQ + col] = acc[mi][ni][r];
      }
}

// ---------------------------------------------------------------------------
// PV: out = P @ v. 512 blocks x 256 thr, 64x128 tiles (waves 2x2 of 32x64:
// MI2/NIv4 = 0.75 reads/MFMA vs 1.0 before), 24 KB LDS -> 4 blocks/CU.
// Tiles sorted K-desc with anti-correlated pairing (t = b<256 ? b : 767-b).
// A = P (bf16 rows inside fp32 S buffer, lda 8192 shorts), B = vT (ldb 4096).
// ---------------------------------------------------------------------------
__global__ __launch_bounds__(256, 4)
void pv_gemm(const short* __restrict__ P, const short* __restrict__ vT,
             float* __restrict__ out) {
  __shared__ short sA[64 * 64];
  __shared__ short sB[128 * 64];
  const int tid = threadIdx.x;
  const int w = tid >> 6, lane = tid & 63;
  const int quad = lane >> 4, l15 = lane & 15;
  const int wm = (w >> 1) * 32, wn = (w & 1) * 64;

  const int t = (blockIdx.x < 256) ? (int)blockIdx.x : 767 - (int)blockIdx.x;
  const int mt = 63 - (t >> 3);  // K-descending
  const int nt = t & 7;
  const int m0 = mt * 64, n0 = nt * 128;
  const int K = ((mt >> 1) + 1) * 128;  // matches softmax padding

  f32x4 acc[2][4];
#pragma unroll
  for (int mi = 0; mi < 2; ++mi)
#pragma unroll
    for (int ni = 0; ni < 4; ++ni)
#pragma unroll
      for (int r = 0; r < 4; ++r) acc[mi][ni][r] = 0.f;

  const int nk = K >> 6;
  for (int kt = 0; kt < nk; ++kt) {
    const int k0 = kt * 64;
    stage_sw<64, false>(P, nullptr, 8192, m0, k0, sA, tid);
    stage_sw<128, false>(vT, nullptr, N_SEQ, n0, k0, sB, tid);
    __syncthreads();
    bf_step<2, 4>(sA, sB, wm, wn, quad, l15, acc);
    __syncthreads();
  }
#pragma unroll
  for (int mi = 0; mi < 2; ++mi)
#pragma unroll
    for (int ni = 0; ni < 4; ++ni)
#pragma unroll
      for (int r = 0; r < 4; ++r) {
        const int row = m0 + wm + mi * 16 + quad * 4 + r;
        const int col = n0 + wn + ni * 16 + l15;
        out[(size_t)row * D_MODEL + col] = acc[mi][ni][r];
      }
}

// ---------------------------------------------------------------------------
// Fused prep, flat grid of 4608 x 256 thr:
//  b < 4096: x elementwise split -> xh, xl
//  b < 4352: wqk 64x64 tile -> wqkTh, wqkTl (transposed, hi+lo)
//  else    : wov tile -> wovT (transposed)
// ---------------------------------------------------------------------------
__global__ __launch_bounds__(256)
void prep_all(const float* __restrict__ x, const float* __restrict__ wqk,
              const float* __restrict__ wov, short* __restrict__ xh,
              short* __restrict__ xl, short* __restrict__ wqkTh,
              short* __restrict__ wqkTl, short* __restrict__ wovT) {
  __shared__ short Th[64][72];
  __shared__ short Tl[64][72];
  const int tid = threadIdx.x;
  const int b = blockIdx.x;

  if (b < 4096) {
    const int idx = b * 256 + tid;
    const float4 v = ((const float4*)x)[idx];
    const float f[4] = {v.x, v.y, v.z, v.w};
    short h[4], l[4];
#pragma unroll
    for (int i = 0; i < 4; ++i) {
      h[i] = f2bf(f[i]);
      l[i] = f2bf(f[i] - bf2f(h[i]));
    }
    ((short4*)xh)[idx] = make_short4(h[0], h[1], h[2], h[3]);
    ((short4*)xl)[idx] = make_short4(l[0], l[1], l[2], l[3]);
    return;
  }

  const bool is_qk = (b < 4352);
  const int local = b - (is_qk ? 4096 : 4352);
  const float* in = is_qk ? wqk : wov;
  short* hiT = is_qk ? wqkTh : wovT;
  short* loT = is_qk ? wqkTl : nullptr;
  const int r0 = (local & 15) * 64, c0 = (local >> 4) * 64;

#pragma unroll
  for (int i = 0; i < 4; ++i) {
    const int rr = (tid >> 4) + i * 16;
    const int cc = (tid & 15) * 4;
    const float4 v = *(const float4*)&in[(size_t)(r0 + rr) * D_MODEL + c0 + cc];
    const float f[4] = {v.x, v.y, v.z, v.w};
#pragma unroll
    for (int j = 0; j < 4; ++j) {
      const short h = f2bf(f[j]);
      Th[rr][cc + j] = h;
      Tl[rr][cc + j] = is_qk ? f2bf(f[j] - bf2f(h)) : (short)0;
    }
  }
  __syncthreads();
#pragma unroll
  for (int i = 0; i < 2; ++i) {
    const int idx = tid + i * 256;
    const int oc = idx >> 3;
    const int ch = (idx & 7) * 8;
    float4 u;
    short* t = (short*)&u;
#pragma unroll
    for (int j = 0; j < 8; ++j) t[j] = Th[ch + j][oc];
    *(float4*)&hiT[(size_t)(c0 + oc) * D_MODEL + r0 + ch] = u;
    if (loT) {
#pragma unroll
      for (int j = 0; j < 8; ++j) t[j] = Tl[ch + j][oc];
      *(float4*)&loT[(size_t)(c0 + oc) * D_MODEL + r0 + ch] = u;
    }
  }
}

// ---------------------------------------------------------------------------
// Row softmax, single pass, in place: S row (fp32) -> P bf16 over the same
// storage. Pads row gi to ((gi>>7)+1)*128 (== PV K for the row's m-tile).
// ---------------------------------------------------------------------------
__global__ __launch_bounds__(256)
void softmax_inplace(float* __restrict__ S, int row0) {
  const int li = blockIdx.x;
  const int gi = row0 + li;
  const int valid = gi + 1;
  const int padded = ((gi >> 7) + 1) << 7;
  const int nf4 = padded >> 2;
  float* srow = S + (size_t)li * N_SEQ;
  short* prow = (short*)srow;
  const int tid = threadIdx.x;
  const int w = tid >> 6, lane = tid & 63;
  __shared__ float wred[4];
  __shared__ float sm, sil;

  float4 v[4];
  float m = -1e30f;
#pragma unroll
  for (int k = 0; k < 4; ++k) {
    const int j = tid + k * 256;
    if (j < nf4) {
      v[k] = ((const float4*)srow)[j];
      float* f = (float*)&v[k];
#pragma unroll
      for (int e = 0; e < 4; ++e)
        if (4 * j + e < valid) m = fmaxf(m, f[e]);
    }
  }
#pragma unroll
  for (int off = 32; off > 0; off >>= 1) m = fmaxf(m, __shfl_down(m, off));
  if (lane == 0) wred[w] = m;
  __syncthreads();
  if (tid == 0) sm = fmaxf(fmaxf(wred[0], wred[1]), fmaxf(wred[2], wred[3]));
  __syncthreads();
  m = sm;

  float l = 0.f;
#pragma unroll
  for (int k = 0; k < 4; ++k) {
    const int j = tid + k * 256;
    if (j < nf4) {
      float* f = (float*)&v[k];
#pragma unroll
      for (int e = 0; e < 4; ++e) {
        const float p = (4 * j + e < valid) ? __expf(f[e] - m) : 0.f;
        f[e] = p;
        l += p;
      }
    }
  }
#pragma unroll
  for (int off = 32; off > 0; off >>= 1) l += __shfl_down(l, off);
  if (lane == 0) wred[w] = l;
  __syncthreads();
  if (tid == 0) sil = 1.f / (wred[0] + wred[1] + wred[2] + wred[3]);
  __syncthreads();
  const float il = sil;

#pragma unroll
  for (int k = 0; k < 4; ++k) {
    const int j = tid + k * 256;
    if (j < nf4) {
      const float* f = (const float*)&v[k];
      *(short4*)&prow[4 * j] = make_short4(f2bf(f[0] * il), f2bf(f[1] * il),
                                           f2bf(f[2] * il), f2bf(f[3] * il));
    }
  }
}

// ---------------------------------------------------------------------------
extern "C" void kernel_launch(void* const* d_in, const int* in_sizes, int n_in,
                              void* d_out, int out_size, void* d_ws,
                              size_t ws_size, hipStream_t stream) {
  (void)in_sizes; (void)n_in; (void)out_size; (void)ws_size;
  const float* x   = (const float*)d_in[0];
  const float* wqk = (const float*)d_in[1];
  const float* wov = (const float*)d_in[2];
  float* out = (float*)d_out;

  const size_t MB = 1ull << 20;
  char* p = (char*)d_ws;
  short* xh    = (short*)(p);             //  8 MB 4096x1024 bf16 hi
  short* xl    = (short*)(p + 8 * MB);    //  8 MB           bf16 lo
  short* wqkTh = (short*)(p + 16 * MB);   //  2 MB
  short* wqkTl = (short*)(p + 18 * MB);   //  2 MB
  short* wovT  = (short*)(p + 20 * MB);   //  2 MB
  short* qh    = (short*)(p + 22 * MB);   //  8 MB
  short* ql    = (short*)(p + 30 * MB);   //  8 MB
  short* vT    = (short*)(p + 38 * MB);   //  8 MB 1024x4096: vT[d][s]=(x@wov)[s][d]
  float* S     = (float*)(p + 46 * MB);   // 64 MB 4096x4096 fp32 (P aliases)
                                          // total 110 MB

  prep_all<<<4608, 256, 0, stream>>>(x, wqk, wov, xh, xl, wqkTh, wqkTl, wovT);
  // fused rect: q = x@wqk (split hi/lo) + vT = (x@wov)^T — mutual drain-fill
  fused_rect<<<512, 256, 0, stream>>>(xh, xl, wqkTh, wqkTl, wovT, qh, ql, vT);
  // S = q @ x^T causal
  qk_causal<<<528, 256, 0, stream>>>(qh, ql, xh, xl, S);
  // softmax rows -> P bf16 in place
  softmax_inplace<<<N_SEQ, 256, 0, stream>>>(S, 0);
  // out = P @ v  (64x128 tiles, MI2/NIv4, 4 blocks/CU, K-desc paired)
  pv_gemm<<<512, 256, 0, stream>>>((const short*)S, vT, out);
}

// Round 11
// 255.728 us; speedup vs baseline: 1.0100x; 1.0100x over previous
//
#include <hip/hip_runtime.h>
#include <hip/hip_bf16.h>
#include <math.h>

#define N_SEQ 4096
#define D_MODEL 1024

typedef __attribute__((ext_vector_type(8))) short short8;
typedef __attribute__((ext_vector_type(4))) float f32x4;

__device__ __forceinline__ short f2bf(float f) {
  __hip_bfloat16 h = __float2bfloat16(f);
  return *reinterpret_cast<short*>(&h);
}
__device__ __forceinline__ float bf2f(short h) {
  return __uint_as_float(((unsigned)(unsigned short)h) << 16);
}

// async global->LDS, 16B per lane. LDS dest must be wave-uniform base + lane*16.
__device__ __forceinline__ void gload16(const short* g, short* l) {
  __builtin_amdgcn_global_load_lds(
      (const __attribute__((address_space(1))) void*)g,
      (__attribute__((address_space(3))) void*)l, 16, 0, 0);
}

// ---------------------------------------------------------------------------
// XOR-swizzled staging (256 thr): tile ROWS x 64 shorts. Slot s (16B):
// r = s>>3, c8 = (s&7)^(r&7) -> fragment ds_read_b128 hits all 32 banks
// (2-way, free — verified R4: conflicts 6.5e6 -> 0). HL: row = [hi 32 | lo 32].
// ---------------------------------------------------------------------------
template <int ROWS, bool HL>
__device__ __forceinline__ void stage_sw(const short* __restrict__ hi,
                                         const short* __restrict__ lo, int ld,
                                         int r0, int k0, short* dst, int tid) {
#pragma unroll
  for (int i = 0; i < ROWS * 8 / 256; ++i) {
    const int s = i * 256 + tid;
    const int r = s >> 3;
    const int c8 = (s & 7) ^ (r & 7);
    const short* src;
    int col;
    if (HL) {
      src = (c8 < 4) ? hi : lo;
      col = (c8 & 3) * 8;
    } else {
      src = hi;
      col = c8 * 8;
    }
    gload16(&src[(size_t)(r0 + r) * ld + k0 + col], &dst[s * 8]);
  }
}

// HL inner step (KSTEP=32): MI x NIv wave tile, 3-product split-bf16.
template <int MI, int NIv>
__device__ __forceinline__ void hl_step(const short* sA, const short* sB,
                                        int wm, int wn, int quad, int l15,
                                        f32x4 acc[MI][NIv]) {
  short8 a[MI], am[MI], b[NIv], bm[NIv];
#pragma unroll
  for (int mi = 0; mi < MI; ++mi) {
    const int rr = wm + mi * 16 + l15;
    a[mi] = *(const short8*)&sA[rr * 64 + ((quad ^ (rr & 7)) << 3)];
    am[mi] = *(const short8*)&sA[rr * 64 + (((quad + 4) ^ (rr & 7)) << 3)];
  }
#pragma unroll
  for (int ni = 0; ni < NIv; ++ni) {
    const int rr = wn + ni * 16 + l15;
    b[ni] = *(const short8*)&sB[rr * 64 + ((quad ^ (rr & 7)) << 3)];
    bm[ni] = *(const short8*)&sB[rr * 64 + (((quad + 4) ^ (rr & 7)) << 3)];
  }
#pragma unroll
  for (int mi = 0; mi < MI; ++mi)
#pragma unroll
    for (int ni = 0; ni < NIv; ++ni) {
      acc[mi][ni] = __builtin_amdgcn_mfma_f32_16x16x32_bf16(a[mi], b[ni],
                                                            acc[mi][ni], 0, 0, 0);
      acc[mi][ni] = __builtin_amdgcn_mfma_f32_16x16x32_bf16(a[mi], bm[ni],
                                                            acc[mi][ni], 0, 0, 0);
      acc[mi][ni] = __builtin_amdgcn_mfma_f32_16x16x32_bf16(am[mi], b[ni],
                                                            acc[mi][ni], 0, 0, 0);
    }
}

// non-HL inner step (KSTEP=64): two k=32 slices.
template <int MI, int NIv>
__device__ __forceinline__ void bf_step(const short* sA, const short* sB,
                                        int wm, int wn, int quad, int l15,
                                        f32x4 acc[MI][NIv]) {
#pragma unroll
  for (int s = 0; s < 2; ++s) {
    short8 a[MI], b[NIv];
#pragma unroll
    for (int mi = 0; mi < MI; ++mi) {
      const int rr = wm + mi * 16 + l15;
      a[mi] = *(const short8*)&sA[rr * 64 + (((s * 4 + quad) ^ (rr & 7)) << 3)];
    }
#pragma unroll
    for (int ni = 0; ni < NIv; ++ni) {
      const int rr = wn + ni * 16 + l15;
      b[ni] = *(const short8*)&sB[rr * 64 + (((s * 4 + quad) ^ (rr & 7)) << 3)];
    }
#pragma unroll
    for (int mi = 0; mi < MI; ++mi)
#pragma unroll
      for (int ni = 0; ni < NIv; ++ni)
        acc[mi][ni] = __builtin_amdgcn_mfma_f32_16x16x32_bf16(
            a[mi], b[ni], acc[mi][ni], 0, 0, 0);
  }
}

// ---------------------------------------------------------------------------
// qproj: q = x @ wqk, 512 blocks x 256 thr, 128x64 tiles (2 blocks/CU),
// HL 3-product, out split qh/ql. (R9-measured config.)
// ---------------------------------------------------------------------------
__global__ __launch_bounds__(256, 2)
void qproj(const short* __restrict__ xh, const short* __restrict__ xl,
           const short* __restrict__ wqkTh, const short* __restrict__ wqkTl,
           short* __restrict__ qh, short* __restrict__ ql) {
  __shared__ short sA[128 * 64];
  __shared__ short sB[64 * 64];
  const int tid = threadIdx.x;
  const int w = tid >> 6, lane = tid & 63;
  const int quad = lane >> 4, l15 = lane & 15;
  const int wm = (w >> 1) * 64, wn = (w & 1) * 32;

  const int mt = blockIdx.x >> 4, nt = blockIdx.x & 15;  // 32 x 16 grid
  const int m0 = mt * 128, n0 = nt * 64;

  f32x4 acc[4][2];
#pragma unroll
  for (int mi = 0; mi < 4; ++mi)
#pragma unroll
    for (int ni = 0; ni < 2; ++ni)
#pragma unroll
      for (int r = 0; r < 4; ++r) acc[mi][ni][r] = 0.f;

  for (int kt = 0; kt < 32; ++kt) {
    const int k0 = kt * 32;
    stage_sw<128, true>(xh, xl, 1024, m0, k0, sA, tid);
    stage_sw<64, true>(wqkTh, wqkTl, 1024, n0, k0, sB, tid);
    __syncthreads();
    hl_step<4, 2>(sA, sB, wm, wn, quad, l15, acc);
    __syncthreads();
  }
#pragma unroll
  for (int mi = 0; mi < 4; ++mi)
#pragma unroll
    for (int ni = 0; ni < 2; ++ni)
#pragma unroll
      for (int r = 0; r < 4; ++r) {
        const int row = m0 + wm + mi * 16 + quad * 4 + r;
        const int col = n0 + wn + ni * 16 + l15;
        const float v = acc[mi][ni][r];
        const short h = f2bf(v);
        qh[(size_t)row * 1024 + col] = h;
        ql[(size_t)row * 1024 + col] = f2bf(v - bf2f(h));
      }
}

// ---------------------------------------------------------------------------
// Fused QK + vT dispatch, 784 blocks x 256 thr (4 waves, 64x64 wave tiles):
//  blocks [0,528): S = q @ x^T causal (supertile-8, split-bf16, fp32 out)
//  blocks [528,784): vT = (x @ wov)^T rect NT GEMM (bf16, ldc 4096)
// vT's short independent blocks fill QK's barrier/vmcnt drains and form the
// tail (R9-measured: 80.1 us for both, MfmaUtil 31.9 vs 28.7 solo).
// ---------------------------------------------------------------------------
__global__ __launch_bounds__(256, 2)
void fused_qk_v(const short* __restrict__ qh, const short* __restrict__ ql,
                const short* __restrict__ xh, const short* __restrict__ xl,
                const short* __restrict__ wovT, float* __restrict__ S,
                short* __restrict__ vT) {
  __shared__ short sA[128 * 64];
  __shared__ short sB[128 * 64];
  const int tid = threadIdx.x;
  const int w = tid >> 6, lane = tid & 63;
  const int quad = lane >> 4, l15 = lane & 15;
  const int wm = (w >> 1) * 64, wn = (w & 1) * 64;

  f32x4 acc[4][4];
#pragma unroll
  for (int mi = 0; mi < 4; ++mi)
#pragma unroll
    for (int ni = 0; ni < 4; ++ni)
#pragma unroll
      for (int r = 0; r < 4; ++r) acc[mi][ni][r] = 0.f;

  if (blockIdx.x < 528) {
    // ---- QK causal, supertile-8 decode ----
    const int f = blockIdx.x;
    int R;
    if (f < 36) R = 0;
    else if (f < 136) R = 1;
    else if (f < 300) R = 2;
    else R = 3;
    const int rem = f - (32 * R * R + 4 * R);
    const int full = R << 6;
    int mt, nt;
    if (rem < full) {
      const int C = rem >> 6, ww = rem & 63;
      mt = 8 * R + (ww >> 3);
      nt = 8 * C + (ww & 7);
    } else {
      const int d = rem - full;
      int lm = 0;
      while ((lm + 1) * (lm + 2) / 2 <= d) ++lm;
      mt = 8 * R + lm;
      nt = 8 * R + d - lm * (lm + 1) / 2;
    }
    const int m0 = mt * 128, n0 = nt * 128;
    for (int kt = 0; kt < 32; ++kt) {
      const int k0 = kt * 32;
      stage_sw<128, true>(qh, ql, 1024, m0, k0, sA, tid);
      stage_sw<128, true>(xh, xl, 1024, n0, k0, sB, tid);
      __syncthreads();
      hl_step<4, 4>(sA, sB, wm, wn, quad, l15, acc);
      __syncthreads();
    }
#pragma unroll
    for (int mi = 0; mi < 4; ++mi)
#pragma unroll
      for (int ni = 0; ni < 4; ++ni)
#pragma unroll
        for (int r = 0; r < 4; ++r) {
          const int row = m0 + wm + mi * 16 + quad * 4 + r;
          const int col = n0 + wn + ni * 16 + l15;
          S[(size_t)row * N_SEQ + col] = acc[mi][ni][r];
        }
  } else {
    // ---- vT = (x @ wov)^T : C[m][n] = sum_d wovT[m][d] * xh[n][d] ----
    const int f2 = blockIdx.x - 528;
    const int mt = f2 >> 5, nt = f2 & 31;
    const int m0 = mt * 128, n0 = nt * 128;
    for (int kt = 0; kt < 16; ++kt) {
      const int k0 = kt * 64;
      stage_sw<128, false>(wovT, nullptr, 1024, m0, k0, sA, tid);
      stage_sw<128, false>(xh, nullptr, 1024, n0, k0, sB, tid);
      __syncthreads();
      bf_step<4, 4>(sA, sB, wm, wn, quad, l15, acc);
      __syncthreads();
    }
#pragma unroll
    for (int mi = 0; mi < 4; ++mi)
#pragma unroll
      for (int ni = 0; ni < 4; ++ni)
#pragma unroll
        for (int r = 0; r < 4; ++r) {
          const int row = m0 + wm + mi * 16 + quad * 4 + r;
          const int col = n0 + wn + ni * 16 + l15;
          vT[(size_t)row * N_SEQ + col] = f2bf(acc[mi][ni][r]);
        }
  }
}

// ---------------------------------------------------------------------------
// PV: out = P @ v. 512 blocks x 256 thr, 64x128 tiles (waves 2x2 of 32x64),
// 24 KB LDS -> 4 blocks/CU residency for drain hiding. K-desc order with
// anti-correlated pairing (t = b<256 ? b : 767-b) balances CU loads.
// A = P (bf16 rows inside fp32 S buffer, lda 8192 shorts), B = vT (ldb 4096).
// ---------------------------------------------------------------------------
__global__ __launch_bounds__(256, 4)
void pv_gemm(const short* __restrict__ P, const short* __restrict__ vT,
             float* __restrict__ out) {
  __shared__ short sA[64 * 64];
  __shared__ short sB[128 * 64];
  const int tid = threadIdx.x;
  const int w = tid >> 6, lane = tid & 63;
  const int quad = lane >> 4, l15 = lane & 15;
  const int wm = (w >> 1) * 32, wn = (w & 1) * 64;

  const int t = (blockIdx.x < 256) ? (int)blockIdx.x : 767 - (int)blockIdx.x;
  const int mt = 63 - (t >> 3);  // K-descending
  const int nt = t & 7;
  const int m0 = mt * 64, n0 = nt * 128;
  const int K = ((mt >> 1) + 1) * 128;  // matches softmax padding

  f32x4 acc[2][4];
#pragma unroll
  for (int mi = 0; mi < 2; ++mi)
#pragma unroll
    for (int ni = 0; ni < 4; ++ni)
#pragma unroll
      for (int r = 0; r < 4; ++r) acc[mi][ni][r] = 0.f;

  const int nk = K >> 6;
  for (int kt = 0; kt < nk; ++kt) {
    const int k0 = kt * 64;
    stage_sw<64, false>(P, nullptr, 8192, m0, k0, sA, tid);
    stage_sw<128, false>(vT, nullptr, N_SEQ, n0, k0, sB, tid);
    __syncthreads();
    bf_step<2, 4>(sA, sB, wm, wn, quad, l15, acc);
    __syncthreads();
  }
#pragma unroll
  for (int mi = 0; mi < 2; ++mi)
#pragma unroll
    for (int ni = 0; ni < 4; ++ni)
#pragma unroll
      for (int r = 0; r < 4; ++r) {
        const int row = m0 + wm + mi * 16 + quad * 4 + r;
        const int col = n0 + wn + ni * 16 + l15;
        out[(size_t)row * D_MODEL + col] = acc[mi][ni][r];
      }
}

// ---------------------------------------------------------------------------
// Fused prep, flat grid of 4608 x 256 thr:
//  b < 4096: x elementwise split -> xh, xl
//  b < 4352: wqk 64x64 tile -> wqkTh, wqkTl (transposed, hi+lo)
//  else    : wov tile -> wovT (transposed)
// ---------------------------------------------------------------------------
__global__ __launch_bounds__(256)
void prep_all(const float* __restrict__ x, const float* __restrict__ wqk,
              const float* __restrict__ wov, short* __restrict__ xh,
              short* __restrict__ xl, short* __restrict__ wqkTh,
              short* __restrict__ wqkTl, short* __restrict__ wovT) {
  __shared__ short Th[64][72];
  __shared__ short Tl[64][72];
  const int tid = threadIdx.x;
  const int b = blockIdx.x;

  if (b < 4096) {
    const int idx = b * 256 + tid;
    const float4 v = ((const float4*)x)[idx];
    const float f[4] = {v.x, v.y, v.z, v.w};
    short h[4], l[4];
#pragma unroll
    for (int i = 0; i < 4; ++i) {
      h[i] = f2bf(f[i]);
      l[i] = f2bf(f[i] - bf2f(h[i]));
    }
    ((short4*)xh)[idx] = make_short4(h[0], h[1], h[2], h[3]);
    ((short4*)xl)[idx] = make_short4(l[0], l[1], l[2], l[3]);
    return;
  }

  const bool is_qk = (b < 4352);
  const int local = b - (is_qk ? 4096 : 4352);
  const float* in = is_qk ? wqk : wov;
  short* hiT = is_qk ? wqkTh : wovT;
  short* loT = is_qk ? wqkTl : nullptr;
  const int r0 = (local & 15) * 64, c0 = (local >> 4) * 64;

#pragma unroll
  for (int i = 0; i < 4; ++i) {
    const int rr = (tid >> 4) + i * 16;
    const int cc = (tid & 15) * 4;
    const float4 v = *(const float4*)&in[(size_t)(r0 + rr) * D_MODEL + c0 + cc];
    const float f[4] = {v.x, v.y, v.z, v.w};
#pragma unroll
    for (int j = 0; j < 4; ++j) {
      const short h = f2bf(f[j]);
      Th[rr][cc + j] = h;
      Tl[rr][cc + j] = is_qk ? f2bf(f[j] - bf2f(h)) : (short)0;
    }
  }
  __syncthreads();
#pragma unroll
  for (int i = 0; i < 2; ++i) {
    const int idx = tid + i * 256;
    const int oc = idx >> 3;
    const int ch = (idx & 7) * 8;
    float4 u;
    short* t = (short*)&u;
#pragma unroll
    for (int j = 0; j < 8; ++j) t[j] = Th[ch + j][oc];
    *(float4*)&hiT[(size_t)(c0 + oc) * D_MODEL + r0 + ch] = u;
    if (loT) {
#pragma unroll
      for (int j = 0; j < 8; ++j) t[j] = Tl[ch + j][oc];
      *(float4*)&loT[(size_t)(c0 + oc) * D_MODEL + r0 + ch] = u;
    }
  }
}

// ---------------------------------------------------------------------------
// Row softmax, single pass, in place: S row (fp32) -> P bf16 over the same
// storage. Pads row gi to ((gi>>7)+1)*128 (== PV K for the row's m-tile).
// ---------------------------------------------------------------------------
__global__ __launch_bounds__(256)
void softmax_inplace(float* __restrict__ S, int row0) {
  const int li = blockIdx.x;
  const int gi = row0 + li;
  const int valid = gi + 1;
  const int padded = ((gi >> 7) + 1) << 7;
  const int nf4 = padded >> 2;
  float* srow = S + (size_t)li * N_SEQ;
  short* prow = (short*)srow;
  const int tid = threadIdx.x;
  const int w = tid >> 6, lane = tid & 63;
  __shared__ float wred[4];
  __shared__ float sm, sil;

  float4 v[4];
  float m = -1e30f;
#pragma unroll
  for (int k = 0; k < 4; ++k) {
    const int j = tid + k * 256;
    if (j < nf4) {
      v[k] = ((const float4*)srow)[j];
      float* f = (float*)&v[k];
#pragma unroll
      for (int e = 0; e < 4; ++e)
        if (4 * j + e < valid) m = fmaxf(m, f[e]);
    }
  }
#pragma unroll
  for (int off = 32; off > 0; off >>= 1) m = fmaxf(m, __shfl_down(m, off));
  if (lane == 0) wred[w] = m;
  __syncthreads();
  if (tid == 0) sm = fmaxf(fmaxf(wred[0], wred[1]), fmaxf(wred[2], wred[3]));
  __syncthreads();
  m = sm;

  float l = 0.f;
#pragma unroll
  for (int k = 0; k < 4; ++k) {
    const int j = tid + k * 256;
    if (j < nf4) {
      float* f = (float*)&v[k];
#pragma unroll
      for (int e = 0; e < 4; ++e) {
        const float p = (4 * j + e < valid) ? __expf(f[e] - m) : 0.f;
        f[e] = p;
        l += p;
      }
    }
  }
#pragma unroll
  for (int off = 32; off > 0; off >>= 1) l += __shfl_down(l, off);
  if (lane == 0) wred[w] = l;
  __syncthreads();
  if (tid == 0) sil = 1.f / (wred[0] + wred[1] + wred[2] + wred[3]);
  __syncthreads();
  const float il = sil;

#pragma unroll
  for (int k = 0; k < 4; ++k) {
    const int j = tid + k * 256;
    if (j < nf4) {
      const float* f = (const float*)&v[k];
      *(short4*)&prow[4 * j] = make_short4(f2bf(f[0] * il), f2bf(f[1] * il),
                                           f2bf(f[2] * il), f2bf(f[3] * il));
    }
  }
}

// ---------------------------------------------------------------------------
extern "C" void kernel_launch(void* const* d_in, const int* in_sizes, int n_in,
                              void* d_out, int out_size, void* d_ws,
                              size_t ws_size, hipStream_t stream) {
  (void)in_sizes; (void)n_in; (void)out_size; (void)ws_size;
  const float* x   = (const float*)d_in[0];
  const float* wqk = (const float*)d_in[1];
  const float* wov = (const float*)d_in[2];
  float* out = (float*)d_out;

  const size_t MB = 1ull << 20;
  char* p = (char*)d_ws;
  short* xh    = (short*)(p);             //  8 MB 4096x1024 bf16 hi
  short* xl    = (short*)(p + 8 * MB);    //  8 MB           bf16 lo
  short* wqkTh = (short*)(p + 16 * MB);   //  2 MB
  short* wqkTl = (short*)(p + 18 * MB);   //  2 MB
  short* wovT  = (short*)(p + 20 * MB);   //  2 MB
  short* qh    = (short*)(p + 22 * MB);   //  8 MB
  short* ql    = (short*)(p + 30 * MB);   //  8 MB
  short* vT    = (short*)(p + 38 * MB);   //  8 MB 1024x4096: vT[d][s]=(x@wov)[s][d]
  float* S     = (float*)(p + 46 * MB);   // 64 MB 4096x4096 fp32 (P aliases)
                                          // total 110 MB

  prep_all<<<4608, 256, 0, stream>>>(x, wqk, wov, xh, xl, wqkTh, wqkTl, wovT);
  // q = x @ wqk  (split-bf16 3-product, 128x64 tiles, 512 blocks = 2/CU)
  qproj<<<512, 256, 0, stream>>>(xh, xl, wqkTh, wqkTl, qh, ql);
  // fused: S = q @ x^T causal (528 blocks) + vT = (x@wov)^T (256 blocks)
  fused_qk_v<<<784, 256, 0, stream>>>(qh, ql, xh, xl, wovT, S, vT);
  // softmax rows -> P bf16 in place
  softmax_inplace<<<N_SEQ, 256, 0, stream>>>(S, 0);
  // out = P @ v  (64x128 tiles, 4 blocks/CU, K-desc paired)
  pv_gemm<<<512, 256, 0, stream>>>((const short*)S, vT, out);
}

// Round 12
// 239.387 us; speedup vs baseline: 1.0790x; 1.0683x over previous
//
#include <hip/hip_runtime.h>
#include <hip/hip_bf16.h>
#include <math.h>

#define N_SEQ 4096
#define D_MODEL 1024
#define CAND_CAP 512

typedef __attribute__((ext_vector_type(8))) short short8;
typedef __attribute__((ext_vector_type(4))) float f32x4;

__device__ __forceinline__ short f2bf(float f) {
  __hip_bfloat16 h = __float2bfloat16(f);
  return *reinterpret_cast<short*>(&h);
}
__device__ __forceinline__ float bf2f(short h) {
  return __uint_as_float(((unsigned)(unsigned short)h) << 16);
}

// async global->LDS, 16B per lane. LDS dest must be wave-uniform base + lane*16.
__device__ __forceinline__ void gload16(const short* g, short* l) {
  __builtin_amdgcn_global_load_lds(
      (const __attribute__((address_space(1))) void*)g,
      (__attribute__((address_space(3))) void*)l, 16, 0, 0);
}

// ---------------------------------------------------------------------------
// XOR-swizzled staging (NT thr): tile ROWS x 64 shorts. Slot s (16B):
// r = s>>3, c8 = (s&7)^(r&7) -> fragment ds_read_b128 hits all 32 banks
// (2-way, free — verified R4: conflicts 6.5e6 -> 0). HL: row = [hi 32 | lo 32].
// ---------------------------------------------------------------------------
template <int ROWS, bool HL, int NT>
__device__ __forceinline__ void stage_sw(const short* __restrict__ hi,
                                         const short* __restrict__ lo, int ld,
                                         int r0, int k0, short* dst, int tid) {
#pragma unroll
  for (int i = 0; i < ROWS * 8 / NT; ++i) {
    const int s = i * NT + tid;
    const int r = s >> 3;
    const int c8 = (s & 7) ^ (r & 7);
    const short* src;
    int col;
    if (HL) {
      src = (c8 < 4) ? hi : lo;
      col = (c8 & 3) * 8;
    } else {
      src = hi;
      col = c8 * 8;
    }
    gload16(&src[(size_t)(r0 + r) * ld + k0 + col], &dst[s * 8]);
  }
}

// HL inner step (KSTEP=32): MI x NIv wave tile, 3-product split-bf16.
template <int MI, int NIv>
__device__ __forceinline__ void hl_step(const short* sA, const short* sB,
                                        int wm, int wn, int quad, int l15,
                                        f32x4 acc[MI][NIv]) {
  short8 a[MI], am[MI], b[NIv], bm[NIv];
#pragma unroll
  for (int mi = 0; mi < MI; ++mi) {
    const int rr = wm + mi * 16 + l15;
    a[mi] = *(const short8*)&sA[rr * 64 + ((quad ^ (rr & 7)) << 3)];
    am[mi] = *(const short8*)&sA[rr * 64 + (((quad + 4) ^ (rr & 7)) << 3)];
  }
#pragma unroll
  for (int ni = 0; ni < NIv; ++ni) {
    const int rr = wn + ni * 16 + l15;
    b[ni] = *(const short8*)&sB[rr * 64 + ((quad ^ (rr & 7)) << 3)];
    bm[ni] = *(const short8*)&sB[rr * 64 + (((quad + 4) ^ (rr & 7)) << 3)];
  }
#pragma unroll
  for (int mi = 0; mi < MI; ++mi)
#pragma unroll
    for (int ni = 0; ni < NIv; ++ni) {
      acc[mi][ni] = __builtin_amdgcn_mfma_f32_16x16x32_bf16(a[mi], b[ni],
                                                            acc[mi][ni], 0, 0, 0);
      acc[mi][ni] = __builtin_amdgcn_mfma_f32_16x16x32_bf16(a[mi], bm[ni],
                                                            acc[mi][ni], 0, 0, 0);
      acc[mi][ni] = __builtin_amdgcn_mfma_f32_16x16x32_bf16(am[mi], b[ni],
                                                            acc[mi][ni], 0, 0, 0);
    }
}

// non-HL inner step (KSTEP=64): two k=32 slices.
template <int MI, int NIv>
__device__ __forceinline__ void bf_step(const short* sA, const short* sB,
                                        int wm, int wn, int quad, int l15,
                                        f32x4 acc[MI][NIv]) {
#pragma unroll
  for (int s = 0; s < 2; ++s) {
    short8 a[MI], b[NIv];
#pragma unroll
    for (int mi = 0; mi < MI; ++mi) {
      const int rr = wm + mi * 16 + l15;
      a[mi] = *(const short8*)&sA[rr * 64 + (((s * 4 + quad) ^ (rr & 7)) << 3)];
    }
#pragma unroll
    for (int ni = 0; ni < NIv; ++ni) {
      const int rr = wn + ni * 16 + l15;
      b[ni] = *(const short8*)&sB[rr * 64 + (((s * 4 + quad) ^ (rr & 7)) << 3)];
    }
#pragma unroll
    for (int mi = 0; mi < MI; ++mi)
#pragma unroll
      for (int ni = 0; ni < NIv; ++ni)
        acc[mi][ni] = __builtin_amdgcn_mfma_f32_16x16x32_bf16(
            a[mi], b[ni], acc[mi][ni], 0, 0, 0);
  }
}

// ---------------------------------------------------------------------------
// qproj: q = x @ wqk, 512 blocks x 256 thr, 128x64 tiles (2 blocks/CU),
// HL 3-product (q must be fp32-grade: refinement + scores build on it).
// ---------------------------------------------------------------------------
__global__ __launch_bounds__(256, 2)
void qproj(const short* __restrict__ xh, const short* __restrict__ xl,
           const short* __restrict__ wqkTh, const short* __restrict__ wqkTl,
           short* __restrict__ qh, short* __restrict__ ql) {
  __shared__ short sA[128 * 64];
  __shared__ short sB[64 * 64];
  const int tid = threadIdx.x;
  const int w = tid >> 6, lane = tid & 63;
  const int quad = lane >> 4, l15 = lane & 15;
  const int wm = (w >> 1) * 64, wn = (w & 1) * 32;

  const int mt = blockIdx.x >> 4, nt = blockIdx.x & 15;  // 32 x 16 grid
  const int m0 = mt * 128, n0 = nt * 64;

  f32x4 acc[4][2];
#pragma unroll
  for (int mi = 0; mi < 4; ++mi)
#pragma unroll
    for (int ni = 0; ni < 2; ++ni)
#pragma unroll
      for (int r = 0; r < 4; ++r) acc[mi][ni][r] = 0.f;

  for (int kt = 0; kt < 32; ++kt) {
    const int k0 = kt * 32;
    stage_sw<128, true, 256>(xh, xl, 1024, m0, k0, sA, tid);
    stage_sw<64, true, 256>(wqkTh, wqkTl, 1024, n0, k0, sB, tid);
    __syncthreads();
    hl_step<4, 2>(sA, sB, wm, wn, quad, l15, acc);
    __syncthreads();
  }
#pragma unroll
  for (int mi = 0; mi < 4; ++mi)
#pragma unroll
    for (int ni = 0; ni < 2; ++ni)
#pragma unroll
      for (int r = 0; r < 4; ++r) {
        const int row = m0 + wm + mi * 16 + quad * 4 + r;
        const int col = n0 + wn + ni * 16 + l15;
        const float v = acc[mi][ni][r];
        const short h = f2bf(v);
        qh[(size_t)row * 1024 + col] = h;
        ql[(size_t)row * 1024 + col] = f2bf(v - bf2f(h));
      }
}

// ---------------------------------------------------------------------------
// Fused QK + vT dispatch, 784 blocks x 256 thr (4 waves, 64x64 wave tiles):
//  blocks [0,528): S~ = qh @ xh^T causal (supertile-8, 1-PRODUCT bf16 —
//    estimate only; score error sigma~1.7, refined exactly in softmax for
//    entries near the row max)
//  blocks [528,784): vT = (x @ wov)^T rect NT GEMM (bf16, ldc 4096)
// All blocks now ~equal length (16 K-iters) — uniform 3 blocks/CU.
// ---------------------------------------------------------------------------
__global__ __launch_bounds__(256, 2)
void fused_qk_v(const short* __restrict__ qh, const short* __restrict__ xh,
                const short* __restrict__ wovT, float* __restrict__ S,
                short* __restrict__ vT) {
  __shared__ short sA[128 * 64];
  __shared__ short sB[128 * 64];
  const int tid = threadIdx.x;
  const int w = tid >> 6, lane = tid & 63;
  const int quad = lane >> 4, l15 = lane & 15;
  const int wm = (w >> 1) * 64, wn = (w & 1) * 64;

  f32x4 acc[4][4];
#pragma unroll
  for (int mi = 0; mi < 4; ++mi)
#pragma unroll
    for (int ni = 0; ni < 4; ++ni)
#pragma unroll
      for (int r = 0; r < 4; ++r) acc[mi][ni][r] = 0.f;

  if (blockIdx.x < 528) {
    // ---- QK causal estimate, supertile-8 decode ----
    const int f = blockIdx.x;
    int R;
    if (f < 36) R = 0;
    else if (f < 136) R = 1;
    else if (f < 300) R = 2;
    else R = 3;
    const int rem = f - (32 * R * R + 4 * R);
    const int full = R << 6;
    int mt, nt;
    if (rem < full) {
      const int C = rem >> 6, ww = rem & 63;
      mt = 8 * R + (ww >> 3);
      nt = 8 * C + (ww & 7);
    } else {
      const int d = rem - full;
      int lm = 0;
      while ((lm + 1) * (lm + 2) / 2 <= d) ++lm;
      mt = 8 * R + lm;
      nt = 8 * R + d - lm * (lm + 1) / 2;
    }
    const int m0 = mt * 128, n0 = nt * 128;
    for (int kt = 0; kt < 16; ++kt) {
      const int k0 = kt * 64;
      stage_sw<128, false, 256>(qh, nullptr, 1024, m0, k0, sA, tid);
      stage_sw<128, false, 256>(xh, nullptr, 1024, n0, k0, sB, tid);
      __syncthreads();
      bf_step<4, 4>(sA, sB, wm, wn, quad, l15, acc);
      __syncthreads();
    }
#pragma unroll
    for (int mi = 0; mi < 4; ++mi)
#pragma unroll
      for (int ni = 0; ni < 4; ++ni)
#pragma unroll
        for (int r = 0; r < 4; ++r) {
          const int row = m0 + wm + mi * 16 + quad * 4 + r;
          const int col = n0 + wn + ni * 16 + l15;
          S[(size_t)row * N_SEQ + col] = acc[mi][ni][r];
        }
  } else {
    // ---- vT = (x @ wov)^T : C[m][n] = sum_d wovT[m][d] * xh[n][d] ----
    const int f2 = blockIdx.x - 528;
    const int mt = f2 >> 5, nt = f2 & 31;
    const int m0 = mt * 128, n0 = nt * 128;
    for (int kt = 0; kt < 16; ++kt) {
      const int k0 = kt * 64;
      stage_sw<128, false, 256>(wovT, nullptr, 1024, m0, k0, sA, tid);
      stage_sw<128, false, 256>(xh, nullptr, 1024, n0, k0, sB, tid);
      __syncthreads();
      bf_step<4, 4>(sA, sB, wm, wn, quad, l15, acc);
      __syncthreads();
    }
#pragma unroll
    for (int mi = 0; mi < 4; ++mi)
#pragma unroll
      for (int ni = 0; ni < 4; ++ni)
#pragma unroll
        for (int r = 0; r < 4; ++r) {
          const int row = m0 + wm + mi * 16 + quad * 4 + r;
          const int col = n0 + wn + ni * 16 + l15;
          vT[(size_t)row * N_SEQ + col] = f2bf(acc[mi][ni][r]);
        }
  }
}

// ---------------------------------------------------------------------------
// Softmax + sparse exact refinement, one block (256 thr) per row, in place.
// 1. m~ = max of estimates; 2. candidates = {j : s~ > m~ - 40} (typ. 1-5;
//    all entries within ~20 of the true max are guaranteed included given
//    |s~-s| <~ 10); 3. each candidate recomputed exactly in fp32 VALU:
//    s = (qh+ql)_i . (xh+xl)_j, q-row cached fp32 in LDS; 4. standard
//    max/sum/write over the corrected row -> P bf16 (pads to ((gi>>7)+1)*128).
// Unrefined entries: true weight <= e^-20, computed <= e^-30 — negligible.
// ---------------------------------------------------------------------------
__global__ __launch_bounds__(256)
void softmax_refine(float* __restrict__ S, const short* __restrict__ qh,
                    const short* __restrict__ ql, const short* __restrict__ xh,
                    const short* __restrict__ xl) {
  const int gi = blockIdx.x;
  const int valid = gi + 1;
  const int padded = ((gi >> 7) + 1) << 7;
  const int nf4 = padded >> 2;
  float* srow = S + (size_t)gi * N_SEQ;
  short* prow = (short*)srow;
  const int tid = threadIdx.x;
  const int w = tid >> 6, lane = tid & 63;
  __shared__ float wred[4];
  __shared__ float sm, sil;
  __shared__ float qf[D_MODEL];
  __shared__ int cand[CAND_CAP];
  __shared__ float refv[CAND_CAP];
  __shared__ int ccnt;

  // load row into regs + estimate max
  float4 v[4];
  float m = -1e30f;
#pragma unroll
  for (int k = 0; k < 4; ++k) {
    const int j4 = tid + k * 256;
    if (j4 < nf4) {
      v[k] = ((const float4*)srow)[j4];
      const float* f = (const float*)&v[k];
#pragma unroll
      for (int e = 0; e < 4; ++e)
        if (4 * j4 + e < valid) m = fmaxf(m, f[e]);
    }
  }
#pragma unroll
  for (int off = 32; off > 0; off >>= 1) m = fmaxf(m, __shfl_down(m, off));
  if (lane == 0) wred[w] = m;
  // build fp32 q row in LDS (exactly one short4 per thread: D/4 == 256)
  {
    const short4 hq = ((const short4*)(qh + (size_t)gi * D_MODEL))[tid];
    const short4 lq = ((const short4*)(ql + (size_t)gi * D_MODEL))[tid];
    qf[tid * 4 + 0] = bf2f(hq.x) + bf2f(lq.x);
    qf[tid * 4 + 1] = bf2f(hq.y) + bf2f(lq.y);
    qf[tid * 4 + 2] = bf2f(hq.z) + bf2f(lq.z);
    qf[tid * 4 + 3] = bf2f(hq.w) + bf2f(lq.w);
  }
  if (tid == 0) ccnt = 0;
  __syncthreads();
  if (tid == 0) sm = fmaxf(fmaxf(wred[0], wred[1]), fmaxf(wred[2], wred[3]));
  __syncthreads();

  // collect candidates
  const float thr = sm - 40.0f;
#pragma unroll
  for (int k = 0; k < 4; ++k) {
    const int j4 = tid + k * 256;
    if (j4 < nf4) {
      const float* f = (const float*)&v[k];
#pragma unroll
      for (int e = 0; e < 4; ++e) {
        const int j = 4 * j4 + e;
        if (j < valid && f[e] > thr) {
          const int ix = atomicAdd(&ccnt, 1);
          if (ix < CAND_CAP) cand[ix] = j;
        }
      }
    }
  }
  __syncthreads();
  const int nc = min(ccnt, CAND_CAP);

  // exact fp32 dot for each candidate (block-cooperative)
  for (int c = 0; c < nc; ++c) {
    const int j = cand[c];
    const short* xhr = xh + (size_t)j * D_MODEL;
    const short* xlr = xl + (size_t)j * D_MODEL;
    float part = 0.f;
#pragma unroll
    for (int s = 0; s < 4; ++s) {
      const int d = tid + s * 256;
      part += qf[d] * (bf2f(xhr[d]) + bf2f(xlr[d]));
    }
#pragma unroll
    for (int off = 32; off > 0; off >>= 1) part += __shfl_down(part, off);
    if (lane == 0) wred[w] = part;
    __syncthreads();
    if (tid == 0) refv[c] = wred[0] + wred[1] + wred[2] + wred[3];
    __syncthreads();
  }

  // owners patch their register copies
  for (int c = 0; c < nc; ++c) {
    const int j = cand[c];
    const int j4 = j >> 2;
    if ((j4 & 255) == tid) ((float*)&v[j4 >> 8])[j & 3] = refv[c];
  }

  // exact max over corrected row
  m = -1e30f;
#pragma unroll
  for (int k = 0; k < 4; ++k) {
    const int j4 = tid + k * 256;
    if (j4 < nf4) {
      const float* f = (const float*)&v[k];
#pragma unroll
      for (int e = 0; e < 4; ++e)
        if (4 * j4 + e < valid) m = fmaxf(m, f[e]);
    }
  }
#pragma unroll
  for (int off = 32; off > 0; off >>= 1) m = fmaxf(m, __shfl_down(m, off));
  if (lane == 0) wred[w] = m;
  __syncthreads();
  if (tid == 0) sm = fmaxf(fmaxf(wred[0], wred[1]), fmaxf(wred[2], wred[3]));
  __syncthreads();
  m = sm;

  // sum
  float l = 0.f;
#pragma unroll
  for (int k = 0; k < 4; ++k) {
    const int j4 = tid + k * 256;
    if (j4 < nf4) {
      float* f = (float*)&v[k];
#pragma unroll
      for (int e = 0; e < 4; ++e) {
        const float p = (4 * j4 + e < valid) ? __expf(f[e] - m) : 0.f;
        f[e] = p;
        l += p;
      }
    }
  }
#pragma unroll
  for (int off = 32; off > 0; off >>= 1) l += __shfl_down(l, off);
  if (lane == 0) wred[w] = l;
  __syncthreads();
  if (tid == 0) sil = 1.f / (wred[0] + wred[1] + wred[2] + wred[3]);
  __syncthreads();
  const float il = sil;

  // write P bf16 in place
#pragma unroll
  for (int k = 0; k < 4; ++k) {
    const int j4 = tid + k * 256;
    if (j4 < nf4) {
      const float* f = (const float*)&v[k];
      *(short4*)&prow[4 * j4] = make_short4(f2bf(f[0] * il), f2bf(f[1] * il),
                                            f2bf(f[2] * il), f2bf(f[3] * il));
    }
  }
}

// ---------------------------------------------------------------------------
// PV: out = P @ v. R9-measured config: 512 blocks x 512 thr, 128x64 tiles
// (8 waves 4x2, MI2/NIv2), K-desc anti-correlated pairing.
// A = P (bf16 rows inside fp32 S buffer, lda 8192 shorts), B = vT (ldb 4096).
// ---------------------------------------------------------------------------
__global__ __launch_bounds__(512, 4)
void pv_gemm(const short* __restrict__ P, const short* __restrict__ vT,
             float* __restrict__ out) {
  __shared__ short sA[128 * 64];
  __shared__ short sB[64 * 64];
  const int tid = threadIdx.x;
  const int w = tid >> 6, lane = tid & 63;
  const int quad = lane >> 4, l15 = lane & 15;
  const int wm = (w >> 1) * 32, wn = (w & 1) * 32;

  const int t = (blockIdx.x < 256) ? (int)blockIdx.x : 767 - (int)blockIdx.x;
  const int mt = 31 - (t >> 4);  // K-descending
  const int nt = t & 15;
  const int m0 = mt * 128, n0 = nt * 64;
  const int K = (mt + 1) * 128;  // matches softmax padding

  f32x4 acc[2][2];
#pragma unroll
  for (int mi = 0; mi < 2; ++mi)
#pragma unroll
    for (int ni = 0; ni < 2; ++ni)
#pragma unroll
      for (int r = 0; r < 4; ++r) acc[mi][ni][r] = 0.f;

  const int nk = K >> 6;
  for (int kt = 0; kt < nk; ++kt) {
    const int k0 = kt * 64;
    stage_sw<128, false, 512>(P, nullptr, 8192, m0, k0, sA, tid);
    stage_sw<64, false, 512>(vT, nullptr, N_SEQ, n0, k0, sB, tid);
    __syncthreads();
    bf_step<2, 2>(sA, sB, wm, wn, quad, l15, acc);
    __syncthreads();
  }
#pragma unroll
  for (int mi = 0; mi < 2; ++mi)
#pragma unroll
    for (int ni = 0; ni < 2; ++ni)
#pragma unroll
      for (int r = 0; r < 4; ++r) {
        const int row = m0 + wm + mi * 16 + quad * 4 + r;
        const int col = n0 + wn + ni * 16 + l15;
        out[(size_t)row * D_MODEL + col] = acc[mi][ni][r];
      }
}

// ---------------------------------------------------------------------------
// Fused prep, flat grid of 4608 x 256 thr:
//  b < 4096: x elementwise split -> xh, xl
//  b < 4352: wqk 64x64 tile -> wqkTh, wqkTl (transposed, hi+lo)
//  else    : wov tile -> wovT (transposed)
// ---------------------------------------------------------------------------
__global__ __launch_bounds__(256)
void prep_all(const float* __restrict__ x, const float* __restrict__ wqk,
              const float* __restrict__ wov, short* __restrict__ xh,
              short* __restrict__ xl, short* __restrict__ wqkTh,
              short* __restrict__ wqkTl, short* __restrict__ wovT) {
  __shared__ short Th[64][72];
  __shared__ short Tl[64][72];
  const int tid = threadIdx.x;
  const int b = blockIdx.x;

  if (b < 4096) {
    const int idx = b * 256 + tid;
    const float4 v = ((const float4*)x)[idx];
    const float f[4] = {v.x, v.y, v.z, v.w};
    short h[4], l[4];
#pragma unroll
    for (int i = 0; i < 4; ++i) {
      h[i] = f2bf(f[i]);
      l[i] = f2bf(f[i] - bf2f(h[i]));
    }
    ((short4*)xh)[idx] = make_short4(h[0], h[1], h[2], h[3]);
    ((short4*)xl)[idx] = make_short4(l[0], l[1], l[2], l[3]);
    return;
  }

  const bool is_qk = (b < 4352);
  const int local = b - (is_qk ? 4096 : 4352);
  const float* in = is_qk ? wqk : wov;
  short* hiT = is_qk ? wqkTh : wovT;
  short* loT = is_qk ? wqkTl : nullptr;
  const int r0 = (local & 15) * 64, c0 = (local >> 4) * 64;

#pragma unroll
  for (int i = 0; i < 4; ++i) {
    const int rr = (tid >> 4) + i * 16;
    const int cc = (tid & 15) * 4;
    const float4 v = *(const float4*)&in[(size_t)(r0 + rr) * D_MODEL + c0 + cc];
    const float f[4] = {v.x, v.y, v.z, v.w};
#pragma unroll
    for (int j = 0; j < 4; ++j) {
      const short h = f2bf(f[j]);
      Th[rr][cc + j] = h;
      Tl[rr][cc + j] = is_qk ? f2bf(f[j] - bf2f(h)) : (short)0;
    }
  }
  __syncthreads();
#pragma unroll
  for (int i = 0; i < 2; ++i) {
    const int idx = tid + i * 256;
    const int oc = idx >> 3;
    const int ch = (idx & 7) * 8;
    float4 u;
    short* t = (short*)&u;
#pragma unroll
    for (int j = 0; j < 8; ++j) t[j] = Th[ch + j][oc];
    *(float4*)&hiT[(size_t)(c0 + oc) * D_MODEL + r0 + ch] = u;
    if (loT) {
#pragma unroll
      for (int j = 0; j < 8; ++j) t[j] = Tl[ch + j][oc];
      *(float4*)&loT[(size_t)(c0 + oc) * D_MODEL + r0 + ch] = u;
    }
  }
}

// ---------------------------------------------------------------------------
extern "C" void kernel_launch(void* const* d_in, const int* in_sizes, int n_in,
                              void* d_out, int out_size, void* d_ws,
                              size_t ws_size, hipStream_t stream) {
  (void)in_sizes; (void)n_in; (void)out_size; (void)ws_size;
  const float* x   = (const float*)d_in[0];
  const float* wqk = (const float*)d_in[1];
  const float* wov = (const float*)d_in[2];
  float* out = (float*)d_out;

  const size_t MB = 1ull << 20;
  char* p = (char*)d_ws;
  short* xh    = (short*)(p);             //  8 MB 4096x1024 bf16 hi
  short* xl    = (short*)(p + 8 * MB);    //  8 MB           bf16 lo
  short* wqkTh = (short*)(p + 16 * MB);   //  2 MB
  short* wqkTl = (short*)(p + 18 * MB);   //  2 MB
  short* wovT  = (short*)(p + 20 * MB);   //  2 MB
  short* qh    = (short*)(p + 22 * MB);   //  8 MB
  short* ql    = (short*)(p + 30 * MB);   //  8 MB
  short* vT    = (short*)(p + 38 * MB);   //  8 MB 1024x4096: vT[d][s]=(x@wov)[s][d]
  float* S     = (float*)(p + 46 * MB);   // 64 MB 4096x4096 fp32 (P aliases)
                                          // total 110 MB

  prep_all<<<4608, 256, 0, stream>>>(x, wqk, wov, xh, xl, wqkTh, wqkTl, wovT);
  // q = x @ wqk  (split-bf16 3-product — q must be fp32-grade)
  qproj<<<512, 256, 0, stream>>>(xh, xl, wqkTh, wqkTl, qh, ql);
  // fused: S~ = qh @ xh^T causal 1-product estimate + vT = (x@wov)^T
  fused_qk_v<<<784, 256, 0, stream>>>(qh, xh, wovT, S, vT);
  // softmax with sparse exact refinement -> P bf16 in place
  softmax_refine<<<N_SEQ, 256, 0, stream>>>(S, qh, ql, xh, xl);
  // out = P @ v  (R9 512-thr config, K-desc paired)
  pv_gemm<<<512, 512, 0, stream>>>((const short*)S, vT, out);
}